// Round 7
// baseline (366.101 us; speedup 1.0000x reference)
//
#include <hip/hip_runtime.h>
#include <math.h>

#define NNODES 50000
#define NEG_SLOPE 0.2f
#define NB 391       // ceil(50000/128) buckets
#define BW 128       // nodes per bucket
#define CHUNK 4096   // edges per block in bin_scatter (416 blocks > 256 CUs)
#define CAP 8128     // arena slots per bucket in tmp (mean 4224, sigma ~64)

typedef __bf16 bf16x8 __attribute__((ext_vector_type(8)));
typedef float f32x4 __attribute__((ext_vector_type(4)));

// ---------------------------------------------------------------------------
// CSR build: fixed-stride bucket arena for tmp; slot compacted via gcur.
// bcur[NB] doubles as the global compaction cursor (gcur).
// ---------------------------------------------------------------------------
__global__ void init_bcur(int* bcur) {
    int i = blockIdx.x * 256 + threadIdx.x;
    if (i < NB) bcur[i] = i * CAP;
    if (i == NB) bcur[NB] = 0;  // gcur
}

// Per-block: LDS bucket histogram -> one reservation atomic per bucket ->
// write packed (dst&127)<<16|src into block-private contiguous runs of tmp.
__global__ __launch_bounds__(256) void bin_scatter(const int* __restrict__ ei,
                                                   int E, int N, int* bcur,
                                                   int* __restrict__ tmp) {
    __shared__ int lcnt[NB];
    __shared__ int lbase[NB];
    int tid = threadIdx.x;
    int base0 = blockIdx.x * CHUNK;
    int lim = min(base0 + CHUNK, E + N);
    for (int i = tid; i < NB; i += 256) lcnt[i] = 0;
    __syncthreads();
    for (int e = base0 + tid; e < lim; e += 256) {
        int d = (e < E) ? ei[E + e] : e - E;  // row 1 = dst; tail = self-loops
        atomicAdd(&lcnt[d >> 7], 1);
    }
    __syncthreads();
    for (int b = tid; b < NB; b += 256) {
        int c = lcnt[b];
        lbase[b] = c ? atomicAdd(&bcur[b], c) : 0;
    }
    __syncthreads();
    for (int i = tid; i < NB; i += 256) lcnt[i] = 0;
    __syncthreads();
    for (int e = base0 + tid; e < lim; e += 256) {
        int s, d;
        if (e < E) { s = ei[e]; d = ei[E + e]; }
        else       { s = d = e - E; }
        int b = d >> 7;
        int p = atomicAdd(&lcnt[b], 1);
        tmp[lbase[b] + p] = ((d & 127) << 16) | s;  // src < 50000 < 2^16
    }
}

// One block per bucket: per-node LDS count + scan; block reserves m compact
// slots from gcur; writes off/off_end and scatters slot within [cbase,cbase+m).
__global__ __launch_bounds__(256) void csr_finalize(int* __restrict__ bcur,
                                                    const int* __restrict__ tmp,
                                                    int N, int* __restrict__ off,
                                                    int* __restrict__ off_end,
                                                    int* __restrict__ slot) {
    __shared__ int cnt[BW];
    __shared__ int cur[BW];
    __shared__ int cbase_s;
    int b = blockIdx.x, tid = threadIdx.x;
    int base = b * CAP;
    int m = bcur[b] - base;
    if (tid < BW) cnt[tid] = 0;
    __syncthreads();
    for (int i = tid; i < m; i += 256)
        atomicAdd(&cnt[(tmp[base + i] >> 16) & 127], 1);
    __syncthreads();
    if (tid == 0) cbase_s = atomicAdd(&bcur[NB], m);  // compact reservation
    int myv = (tid < BW) ? cnt[tid] : 0;
    for (int o = 1; o < BW; o <<= 1) {
        int u = 0;
        if (tid >= o && tid < BW) u = cnt[tid - o];
        __syncthreads();
        if (tid < BW) cnt[tid] += u;
        __syncthreads();
    }
    if (tid < BW) {
        int ex = cbase_s + cnt[tid] - myv;  // exclusive, compact coords
        cur[tid] = ex;
        int g = b * BW + tid;
        if (g < N) { off[g] = ex; off_end[g] = ex + myv; }
    }
    __syncthreads();
    for (int i = tid; i < m; i += 256) {
        int v = tmp[base + i];
        int k = (v >> 16) & 127;
        int p = atomicAdd(&cur[k], 1);
        slot[p] = v & 0xFFFF;
    }
}

// ---------------------------------------------------------------------------
// prep_w1: W1[512,64] f32 -> bf16, panelized [k/8][n][k%8] for b-fragments.
// ---------------------------------------------------------------------------
__global__ void prep_w1(const float* __restrict__ W1, __bf16* __restrict__ W1b) {
    int i = blockIdx.x * 256 + threadIdx.x;  // over 512*64
    if (i >= 512 * 64) return;
    int k = i >> 6, n = i & 63;
    W1b[((size_t)(k >> 3) * 64 + n) * 8 + (k & 7)] = (__bf16)W1[i];
}

// ---------------------------------------------------------------------------
// gemm1_mfma: H1b[M,64](bf16) = bf16(X[M,512]) @ bf16(W1[512,64]).
// ---------------------------------------------------------------------------
__global__ __launch_bounds__(256) void gemm1_mfma(const float* __restrict__ X,
                                                  const __bf16* __restrict__ W1b,
                                                  __bf16* __restrict__ H1b, int M) {
    __shared__ __bf16 As[2048];  // [kq 0..3][m 0..63][8]
    __shared__ __bf16 Bs[2048];  // [kq 0..3][n 0..63][8]
    int tid = threadIdx.x, wid = tid >> 6, lane = tid & 63;
    int quad = lane >> 4, l15 = lane & 15;
    int m0 = blockIdx.x * 64;
    f32x4 acc[4] = {{0.f, 0.f, 0.f, 0.f}, {0.f, 0.f, 0.f, 0.f},
                    {0.f, 0.f, 0.f, 0.f}, {0.f, 0.f, 0.f, 0.f}};
    int mrow = tid >> 2;   // 0..63 (staging role)
    int kq_w = tid & 3;    // k-chunk (staging role)
    int xrow = min(m0 + mrow, M - 1);  // clamp: garbage rows never stored
    const float* xp = X + (size_t)xrow * 512 + kq_w * 8;
    for (int kb = 0; kb < 16; ++kb) {
        float4 xa = *(const float4*)(xp + kb * 32);
        float4 xb = *(const float4*)(xp + kb * 32 + 4);
        bf16x8 av;
        av[0] = (__bf16)xa.x; av[1] = (__bf16)xa.y;
        av[2] = (__bf16)xa.z; av[3] = (__bf16)xa.w;
        av[4] = (__bf16)xb.x; av[5] = (__bf16)xb.y;
        av[6] = (__bf16)xb.z; av[7] = (__bf16)xb.w;
        *(bf16x8*)(As + ((size_t)kq_w * 64 + mrow) * 8) = av;
        *(bf16x8*)(Bs + ((size_t)wid * 64 + lane) * 8) =
            *(const bf16x8*)(W1b + ((size_t)(kb * 4 + wid) * 64 + lane) * 8);
        __syncthreads();
        bf16x8 af = *(const bf16x8*)(As + ((size_t)quad * 64 + 16 * wid + l15) * 8);
#pragma unroll
        for (int t = 0; t < 4; ++t) {
            bf16x8 bf = *(const bf16x8*)(Bs + ((size_t)quad * 64 + 16 * t + l15) * 8);
            acc[t] = __builtin_amdgcn_mfma_f32_16x16x32_bf16(af, bf, acc[t], 0, 0, 0);
        }
        __syncthreads();
    }
#pragma unroll
    for (int t = 0; t < 4; ++t) {
#pragma unroll
        for (int r = 0; r < 4; ++r) {
            int gm = m0 + 16 * wid + quad * 4 + r;
            if (gm < M) H1b[(size_t)gm * 64 + 16 * t + l15] = (__bf16)acc[t][r];
        }
    }
}

// ---------------------------------------------------------------------------
// att1: a_src1[n,h], a_dst1[n,h] from H1b[n, h*8+c] (bf16)
// ---------------------------------------------------------------------------
__global__ void att1_kernel(const __bf16* __restrict__ H1b,
                            const float* __restrict__ att_src,
                            const float* __restrict__ att_dst,
                            float* __restrict__ a_src, float* __restrict__ a_dst,
                            int N) {
    int idx = blockIdx.x * 256 + threadIdx.x;  // idx = n*8 + h
    if (idx >= N * 8) return;
    int h = idx & 7;
    bf16x8 hv = *(const bf16x8*)(H1b + (size_t)idx * 8);
    const float* sp = att_src + h * 8;
    const float* dp = att_dst + h * 8;
    float as = 0.f, ad = 0.f;
#pragma unroll
    for (int j = 0; j < 8; ++j) {
        float hf = (float)hv[j];
        as += hf * sp[j];
        ad += hf * dp[j];
    }
    a_src[idx] = as;
    a_dst[idx] = ad;
}

// ---------------------------------------------------------------------------
// agg1: wave per dst node, single pass. Gather role: lane = (edge parity,
// channel pair) -> one 4B load (2 bf16 channels) covers 2 edges per VMEM.
// Staging role unchanged: lane = (edge sub, head) computes distinct w.
// ---------------------------------------------------------------------------
__global__ __launch_bounds__(256) void agg1(const int* __restrict__ off,
                                            const int* __restrict__ off_end,
                                            const int* __restrict__ slot,
                                            const __bf16* __restrict__ H1b,
                                            const float* __restrict__ a_src,
                                            const float* __restrict__ a_dst,
                                            const float* __restrict__ b1,
                                            float* __restrict__ H1R) {
    int wid = threadIdx.x >> 6, lane = threadIdx.x & 63;
    int d = blockIdx.x * 4 + wid;  // grid exact: 12500*4 = 50000
    int beg = off[d], end = off_end[d];
    int es = lane >> 3, eh = lane & 7;  // staging: edge es, head eh
    int half = lane >> 5;               // gather: edge parity
    int m = lane & 31;                  // gather: channels 2m, 2m+1
    int ghead = m >> 2;                 // head of channels 2m,2m+1
    float adst_c = a_dst[(size_t)d * 8 + eh];
    float ax = 0.f, ay = 0.f, den_l = 0.f;
    const unsigned short* H1u = (const unsigned short*)H1b;
    for (int i = beg; i < end; i += 8) {
        int j = i + es;
        int jj = (j < end) ? j : (end - 1);
        int s = slot[jj];
        float e = a_src[(size_t)s * 8 + eh] + adst_c;
        e = (e >= 0.f) ? e : NEG_SLOPE * e;
        float w = (j < end) ? __expf(e) : 0.f;
        den_l += w;
#pragma unroll
        for (int q = 0; q < 4; ++q) {
            int eidx = 2 * q + half;
            int sE = __shfl(s, eidx << 3);
            float wE = __shfl(w, (eidx << 3) | ghead);
            unsigned hv = *(const unsigned*)(H1u + (size_t)sE * 64 + 2 * m);
            ax += wE * __uint_as_float(hv << 16);
            ay += wE * __uint_as_float(hv & 0xFFFF0000u);
        }
    }
    // fold edge-parity halves (lane L and L+32 hold same channels)
    ax += __shfl_xor(ax, 32);
    ay += __shfl_xor(ay, 32);
    // den_l at lane L holds partial for head L&7; reduce over es bits
    den_l += __shfl_xor(den_l, 8);
    den_l += __shfl_xor(den_l, 16);
    den_l += __shfl_xor(den_l, 32);
    float den = __shfl(den_l, ghead);
    float inv = 1.f / (den + 1e-16f);
    if (lane < 32) {
        float2 bv = *(const float2*)(b1 + 2 * m);
        float v0 = ax * inv + bv.x;
        float v1 = ay * inv + bv.y;
        v0 = (v0 > 0.f) ? v0 : 0.f;
        v1 = (v1 > 0.f) ? v1 : 0.f;
        *(float2*)(H1R + (size_t)d * 64 + 2 * m) = make_float2(v0, v1);
    }
}

// ---------------------------------------------------------------------------
// GEMM2 + att2 fused: 16 nodes/block (cuts W2 L2 re-reads 4x). Wave wid
// handles nodes nb+4*wid..+3 sequentially; lane = out channel (40 active).
// ---------------------------------------------------------------------------
__global__ __launch_bounds__(256) void gemm2_att2(const float* __restrict__ H1R,
                                                  const float* __restrict__ W2,
                                                  const float* __restrict__ att_src2,
                                                  const float* __restrict__ att_dst2,
                                                  __bf16* __restrict__ H2b,
                                                  float* __restrict__ a_src2,
                                                  float* __restrict__ a_dst2) {
    __shared__ float W2s[64 * 40];
    __shared__ float rows[16][64];
    int tid = threadIdx.x;
    int wid = tid >> 6, lane = tid & 63;
    for (int i = tid; i < 64 * 40; i += 256) W2s[i] = W2[i];
    int nb = blockIdx.x * 16;  // grid exact: 3125*16 = 50000
#pragma unroll
    for (int r = 0; r < 4; ++r)
        rows[r * 4 + wid][lane] = H1R[(size_t)(nb + r * 4 + wid) * 64 + lane];
    __syncthreads();
    int c = lane;
    int cc = (c < 40) ? c : 0;
    float asc = att_src2[cc], adc = att_dst2[cc];
#pragma unroll
    for (int nn = 0; nn < 4; ++nn) {
        int node = nb + wid * 4 + nn;
        const float* rp = rows[wid * 4 + nn];
        float acc = 0.f;
#pragma unroll
        for (int k4 = 0; k4 < 16; ++k4) {
            float4 rv = *(const float4*)(rp + k4 * 4);
            acc += rv.x * W2s[(k4 * 4 + 0) * 40 + cc];
            acc += rv.y * W2s[(k4 * 4 + 1) * 40 + cc];
            acc += rv.z * W2s[(k4 * 4 + 2) * 40 + cc];
            acc += rv.w * W2s[(k4 * 4 + 3) * 40 + cc];
        }
        if (c < 40) H2b[(size_t)node * 40 + c] = (__bf16)acc;
        float ps = (c < 40) ? acc * asc : 0.f;
        float pd = (c < 40) ? acc * adc : 0.f;
#pragma unroll
        for (int mm = 32; mm >= 1; mm >>= 1) {
            ps += __shfl_xor(ps, mm);
            pd += __shfl_xor(pd, mm);
        }
        if (lane == 0) { a_src2[node] = ps; a_dst2[node] = pd; }
    }
}

// ---------------------------------------------------------------------------
// agg2 + bias + log_softmax: wave per dst node, single pass. Gather role:
// 20 lanes/edge x 2 channels -> 3 edges per VMEM (lanes 60-63 idle).
// ---------------------------------------------------------------------------
__global__ __launch_bounds__(256) void agg2(const int* __restrict__ off,
                                            const int* __restrict__ off_end,
                                            const int* __restrict__ slot,
                                            const __bf16* __restrict__ H2b,
                                            const float* __restrict__ a_src2,
                                            const float* __restrict__ a_d2,
                                            const float* __restrict__ b2,
                                            float* __restrict__ out) {
    int wid = threadIdx.x >> 6, lane = threadIdx.x & 63;
    int d = blockIdx.x * 4 + wid;  // grid exact
    int beg = off[d], end = off_end[d];
    float adst = a_d2[d];
    int sub = lane / 20;      // 0..2 edge-in-group; 3 = idle lanes 60-63
    int part = lane % 20;     // channels 2*part, 2*part+1
    float ax = 0.f, ay = 0.f, den = 0.f;
    const unsigned short* H2u = (const unsigned short*)H2b;
    for (int i = beg; i < end; i += 64) {
        int j = i + lane;
        int jj = (j < end) ? j : (end - 1);
        int s = slot[jj];
        float e = a_src2[s] + adst;
        e = (e >= 0.f) ? e : NEG_SLOPE * e;
        float w = (j < end) ? __expf(e) : 0.f;
        den += w;
#pragma unroll
        for (int g = 0; g < 22; ++g) {
            if (i + g * 3 >= end) break;  // uniform branch
            int eidx = g * 3 + sub;       // 0..65
            int el = (eidx < 64) ? eidx : 0;
            int sE = __shfl(s, el);
            float wE = __shfl(w, el);
            if (sub == 3 || eidx >= 64) wE = 0.f;
            unsigned hv = *(const unsigned*)(H2u + (size_t)sE * 40 + 2 * part);
            ax += wE * __uint_as_float(hv << 16);
            ay += wE * __uint_as_float(hv & 0xFFFF0000u);
        }
    }
#pragma unroll
    for (int mm = 32; mm >= 1; mm >>= 1) den += __shfl_xor(den, mm);
    // fold: channel c at lanes {0,20,40}+(c>>1), component c&1
    int c = lane;
    int pc = (c < 40) ? (c >> 1) : 0;
    float v = 0.f;
#pragma unroll
    for (int sb = 0; sb < 3; ++sb) {
        float axs = __shfl(ax, sb * 20 + pc);
        float ays = __shfl(ay, sb * 20 + pc);
        v += (c & 1) ? ays : axs;
    }
    int cc = (c < 40) ? c : 0;
    v = v / (den + 1e-16f) + b2[cc];
    float vm = (c < 40) ? v : -3.0e38f;
#pragma unroll
    for (int mm = 32; mm >= 1; mm >>= 1) vm = fmaxf(vm, __shfl_xor(vm, mm));
    float se = (c < 40) ? __expf(v - vm) : 0.f;
#pragma unroll
    for (int mm = 32; mm >= 1; mm >>= 1) se += __shfl_xor(se, mm);
    float res = v - vm - __logf(se);
    if (c < 40) out[(size_t)d * 40 + c] = res;
}

// ---------------------------------------------------------------------------
extern "C" void kernel_launch(void* const* d_in, const int* in_sizes, int n_in,
                              void* d_out, int out_size, void* d_ws, size_t ws_size,
                              hipStream_t stream) {
    const float* x   = (const float*)d_in[0];
    const int*   ei  = (const int*)d_in[1];
    const float* W1  = (const float*)d_in[2];
    const float* as1 = (const float*)d_in[3];
    const float* ad1 = (const float*)d_in[4];
    const float* b1  = (const float*)d_in[5];
    const float* W2  = (const float*)d_in[6];
    const float* as2 = (const float*)d_in[7];
    const float* ad2 = (const float*)d_in[8];
    const float* b2  = (const float*)d_in[9];
    float* out = (float*)d_out;

    const int N = NNODES;
    const int E = in_sizes[1] / 2;
    const int total = E + N;

    // workspace carve-up
    char* ws = (char*)d_ws;
    size_t o = 0;
    auto alloc = [&](size_t bytes) -> void* {
        void* p = ws + o;
        o = (o + bytes + 255) & ~(size_t)255;
        return p;
    };
    int* bcur    = (int*)alloc((size_t)(NB + 1) * 4);  // +1: gcur at [NB]
    int* off     = (int*)alloc((size_t)N * 4);
    int* off_end = (int*)alloc((size_t)N * 4);
    int* slot    = (int*)alloc((size_t)total * 4);
    __bf16* W1b = (__bf16*)alloc((size_t)512 * 64 * 2);
    __bf16* H1b = (__bf16*)alloc((size_t)N * 64 * 2);
    float* a_s1 = (float*)alloc((size_t)N * 8 * 4);
    float* a_d1 = (float*)alloc((size_t)N * 8 * 4);
    float* H1R  = (float*)alloc((size_t)N * 64 * 4);
    __bf16* H2b = (__bf16*)alloc((size_t)N * 40 * 2);
    float* a_s2 = (float*)alloc((size_t)N * 4);
    float* a_d2 = (float*)alloc((size_t)N * 4);
    int* tmp = (int*)H1R;  // alias: NB*CAP = 3,178,048 ints <= N*64 floats; dead before agg1
    (void)ws_size; (void)n_in; (void)out_size;

    // CSR build (arena tmp + compacted slot; shared by both layers)
    init_bcur<<<(NB + 256) / 256, 256, 0, stream>>>(bcur);
    bin_scatter<<<(total + CHUNK - 1) / CHUNK, 256, 0, stream>>>(ei, E, N, bcur, tmp);
    csr_finalize<<<NB, 256, 0, stream>>>(bcur, tmp, N, off, off_end, slot);

    // Layer 1
    prep_w1<<<(512 * 64 + 255) / 256, 256, 0, stream>>>(W1, W1b);
    gemm1_mfma<<<(N + 63) / 64, 256, 0, stream>>>(x, W1b, H1b, N);
    att1_kernel<<<(N * 8 + 255) / 256, 256, 0, stream>>>(H1b, as1, ad1, a_s1, a_d1, N);
    agg1<<<N / 4, 256, 0, stream>>>(off, off_end, slot, H1b, a_s1, a_d1, b1, H1R);

    // Layer 2
    gemm2_att2<<<N / 16, 256, 0, stream>>>(H1R, W2, as2, ad2, H2b, a_s2, a_d2);
    agg2<<<N / 4, 256, 0, stream>>>(off, off_end, slot, H2b, a_s2, a_d2, b2, out);
}